// Round 3
// baseline (1887.284 us; speedup 1.0000x reference)
//
#include <hip/hip_runtime.h>
#include <cmath>

typedef float    f32x4 __attribute__((ext_vector_type(4)));
typedef _Float16 f16x8 __attribute__((ext_vector_type(8)));

#define T_NUM 4096
#define H_DIM 1024
#define I_DIM 4096
#define MAXTILES 40

// ---- meta layout (int32 indices into the meta block) ----
#define M_COUNTS   0      // [3][2][8]
#define M_CURSORS  48
#define M_OFFSETS  96
#define M_NTILES   144    // [3][2]
#define M_TILE_E   152    // [6][40]
#define M_TILE_M   392    // [6][40]
#define M_TOPKI    1024   // int  [3][4096][2]
#define M_TOPKP    25600  // f32  [3][4096][2]
#define M_STOK     50176  // int  [3][8192]
#define M_SPRB     74752  // f32  [3][8192]

__device__ __forceinline__ float wave_sum(float v) {
  v += __shfl_xor(v, 32);
  v += __shfl_xor(v, 16);
  v += __shfl_xor(v, 8);
  v += __shfl_xor(v, 4);
  v += __shfl_xor(v, 2);
  v += __shfl_xor(v, 1);
  return v;
}

__device__ __forceinline__ void topk_write(int* meta, int layer, int t, const float* v) {
  int e0 = 0; float v0 = v[0];
  #pragma unroll
  for (int e = 1; e < 8; ++e) { if (v[e] > v0) { v0 = v[e]; e0 = e; } }
  int e1 = 0; float v1 = -3.4e38f;
  #pragma unroll
  for (int e = 0; e < 8; ++e) { if (e != e0 && v[e] > v1) { v1 = v[e]; e1 = e; } }
  float ex = expf(v1 - v0);
  float p0 = 1.f / (1.f + ex);
  float p1 = ex / (1.f + ex);
  meta[M_TOPKI + (layer * T_NUM + t) * 2    ] = e0;
  meta[M_TOPKI + (layer * T_NUM + t) * 2 + 1] = e1;
  ((float*)meta)[M_TOPKP + (layer * T_NUM + t) * 2    ] = p0;
  ((float*)meta)[M_TOPKP + (layer * T_NUM + t) * 2 + 1] = p1;
  atomicAdd(&meta[M_COUNTS + (layer * 2 + 0) * 8 + e0], 1);
  atomicAdd(&meta[M_COUNTS + (layer * 2 + 1) * 8 + e1], 1);
}

__global__ __launch_bounds__(256) void router_gu(const float* __restrict__ x,
    const float* __restrict__ Rg, const float* __restrict__ Ru, int* __restrict__ meta)
{
  int w = threadIdx.x >> 6, lane = threadIdx.x & 63;
  int t = blockIdx.x * 4 + w;
  const float* xr = x + (size_t)t * H_DIM + lane * 4;
  f32x4 xv[4];
  #pragma unroll
  for (int c = 0; c < 4; ++c) xv[c] = *(const f32x4*)(xr + c * 256);
  float lg[8], lu[8];
  #pragma unroll
  for (int e = 0; e < 8; ++e) {
    const float* rg = Rg + (size_t)e * H_DIM + lane * 4;
    const float* ru = Ru + (size_t)e * H_DIM + lane * 4;
    float sg = 0.f, su = 0.f;
    #pragma unroll
    for (int c = 0; c < 4; ++c) {
      f32x4 a = *(const f32x4*)(rg + c * 256);
      f32x4 b = *(const f32x4*)(ru + c * 256);
      sg += a[0]*xv[c][0] + a[1]*xv[c][1] + a[2]*xv[c][2] + a[3]*xv[c][3];
      su += b[0]*xv[c][0] + b[1]*xv[c][1] + b[2]*xv[c][2] + b[3]*xv[c][3];
    }
    lg[e] = wave_sum(sg);
    lu[e] = wave_sum(su);
  }
  if (lane == 0) {
    topk_write(meta, 0, t, lg);
    topk_write(meta, 1, t, lu);
  }
}

__global__ void scan_tiles(int* meta, int l0, int nl) {
  if (threadIdx.x != 0 || blockIdx.x != 0) return;
  for (int l = l0; l < l0 + nl; ++l) {
    int off = 0;
    for (int k = 0; k < 2; ++k) {
      int nt = 0;
      for (int e = 0; e < 8; ++e) {
        int s = (l * 2 + k) * 8 + e;
        meta[M_OFFSETS + s] = off;
        int c = meta[M_COUNTS + s];
        for (int m = 0; m < c; m += 128) {
          meta[M_TILE_E + (l * 2 + k) * MAXTILES + nt] = e;
          meta[M_TILE_M + (l * 2 + k) * MAXTILES + nt] = m;
          ++nt;
        }
        off += c;
      }
      meta[M_NTILES + l * 2 + k] = nt;
    }
  }
}

__global__ __launch_bounds__(256) void assign_slots(int* meta, int l0, int nl) {
  int t = blockIdx.x * blockDim.x + threadIdx.x;
  if (t >= T_NUM) return;
  for (int l = l0; l < l0 + nl; ++l) {
    #pragma unroll
    for (int k = 0; k < 2; ++k) {
      int e  = meta[M_TOPKI + (l * T_NUM + t) * 2 + k];
      float p = ((float*)meta)[M_TOPKP + (l * T_NUM + t) * 2 + k];
      int s = (l * 2 + k) * 8 + e;
      int pos = meta[M_OFFSETS + s] + atomicAdd(&meta[M_CURSORS + s], 1);
      meta[M_STOK + l * 8192 + pos] = t;
      ((float*)meta)[M_SPRB + l * 8192 + pos] = p;
    }
  }
}

// Routed GEMM v3: 128xBN tile, BK=32, 4 waves (2x2), mfma_f32_16x16x32_f16.
// W: fp32 direct global->reg fragment loads + in-VALU hi/lo split (no LDS, no
//    pre-convert, no DMA-barrier coupling).
// A: gathered fp32 rows reg-staged -> hi/lo f16 -> LDS double-buffer (32KB).
// One __syncthreads per K-step; va gather issued a full MFMA phase ahead.
template<int SPLITS, int ADD, int N, int BN, int KT>
__global__ __launch_bounds__(256) void moe_gemm3(
    const float* __restrict__ Asrc, const float* __restrict__ Wsrc,
    float* __restrict__ Out, const int* __restrict__ meta, int layer, int kk)
{
  constexpr int K   = KT * 32;
  constexpr int NPL = (SPLITS == 3) ? 2 : 1;
  constexpr int NFR = BN / 32;          // N-fragments per wave (wave covers BN/2 cols)

  int pass = layer * 2 + kk;
  if ((int)blockIdx.x >= meta[M_NTILES + pass]) return;
  int e    = meta[M_TILE_E + pass * MAXTILES + blockIdx.x];
  int m0   = meta[M_TILE_M + pass * MAXTILES + blockIdx.x];
  int sidx = pass * 8 + e;
  int cnt  = meta[M_COUNTS + sidx];
  int seg  = meta[M_OFFSETS + sidx];
  int n0   = blockIdx.y * BN;

  __shared__ __align__(16) _Float16 sA[2 * NPL * 4096];

  int tid = threadIdx.x, lane = tid & 63, w = tid >> 6;
  int wr = w >> 1, wc = w & 1, fr = lane & 15, fq = lane >> 4;
  int r2 = tid >> 1, half = tid & 1;

  const int*   stok = meta + M_STOK + layer * 8192 + seg;
  const float* sprb = (const float*)meta + M_SPRB + layer * 8192 + seg;

  int ma = m0 + r2; if (ma >= cnt) ma = cnt - 1;
  const float* Abase = Asrc + (size_t)stok[ma] * K + half * 16;
  // per-lane W fragment base: row = n0 + wc*(BN/2) + fr (+ni*16), k = fq*8
  const float* Wbase = Wsrc + ((size_t)e * N + n0 + wc * (BN / 2) + fr) * K + fq * 8;

  f32x4 va[4];
  auto loadA = [&](int kt) {
    const float* p = Abase + kt * 32;
    va[0] = *(const f32x4*)p;
    va[1] = *(const f32x4*)(p + 4);
    va[2] = *(const f32x4*)(p + 8);
    va[3] = *(const f32x4*)(p + 12);
  };
  auto writeA = [&](int buf) {
    #pragma unroll
    for (int j = 0; j < 2; ++j) {
      f16x8 h, l;
      #pragma unroll
      for (int q = 0; q < 8; ++q) {
        float v = va[j * 2 + (q >> 2)][q & 3];
        _Float16 hv = (_Float16)v;
        h[q] = hv;
        if constexpr (SPLITS == 3) l[q] = (_Float16)(v - (float)hv);
      }
      int off = ((half * 2 + j) * 128 + r2) * 8;
      *(f16x8*)&sA[buf * (NPL * 4096) + off] = h;
      if constexpr (SPLITS == 3) *(f16x8*)&sA[buf * (NPL * 4096) + 4096 + off] = l;
    }
  };

  int aoff = (fq * 128 + wr * 64 + fr) * 8;  // [fq][row][8] f16, row = wr*64+fr (+mi*16)

  f32x4 acc[4][NFR];
  #pragma unroll
  for (int i = 0; i < 4; ++i)
    #pragma unroll
    for (int j = 0; j < NFR; ++j) acc[i][j] = f32x4{0.f, 0.f, 0.f, 0.f};

  // prologue: A(0) -> buf0
  loadA(0);
  writeA(0);
  __syncthreads();

  #pragma unroll 2
  for (int kt = 0; kt < KT; ++kt) {
    int buf = kt & 1;
    int ktn = (kt + 1 < KT) ? kt + 1 : KT - 1;

    // W fp32 fragment loads for THIS k-step (compiler vmcnt-waits before use)
    f32x4 wf[NFR][2];
    const float* Wk = Wbase + kt * 32;
    #pragma unroll
    for (int ni = 0; ni < NFR; ++ni) {
      wf[ni][0] = *(const f32x4*)(Wk + (size_t)ni * 16 * K);
      wf[ni][1] = *(const f32x4*)(Wk + (size_t)ni * 16 * K + 4);
    }
    // next A gather issued early; consumed by writeA after the MFMA phase
    loadA(ktn);

    // A fragments from LDS
    f16x8 ah[4], al[(SPLITS == 3) ? 4 : 1];
    const _Float16* A0 = sA + buf * (NPL * 4096);
    #pragma unroll
    for (int mi = 0; mi < 4; ++mi) ah[mi] = *(const f16x8*)(A0 + aoff + mi * 128);
    if constexpr (SPLITS == 3) {
      #pragma unroll
      for (int mi = 0; mi < 4; ++mi) al[mi] = *(const f16x8*)(A0 + 4096 + aoff + mi * 128);
    }

    // W split in VALU
    f16x8 bh[NFR], bl[(SPLITS == 3) ? NFR : 1];
    #pragma unroll
    for (int ni = 0; ni < NFR; ++ni) {
      #pragma unroll
      for (int q = 0; q < 8; ++q) {
        float v = wf[ni][q >> 2][q & 3];
        _Float16 hv = (_Float16)v;
        bh[ni][q] = hv;
        if constexpr (SPLITS == 3) bl[ni][q] = (_Float16)(v - (float)hv);
      }
    }

    __builtin_amdgcn_s_setprio(1);
    #pragma unroll
    for (int mi = 0; mi < 4; ++mi)
      #pragma unroll
      for (int ni = 0; ni < NFR; ++ni)
        acc[mi][ni] = __builtin_amdgcn_mfma_f32_16x16x32_f16(ah[mi], bh[ni], acc[mi][ni], 0, 0, 0);
    if constexpr (SPLITS == 3) {
      #pragma unroll
      for (int mi = 0; mi < 4; ++mi)
        #pragma unroll
        for (int ni = 0; ni < NFR; ++ni)
          acc[mi][ni] = __builtin_amdgcn_mfma_f32_16x16x32_f16(ah[mi], bl[ni], acc[mi][ni], 0, 0, 0);
      #pragma unroll
      for (int mi = 0; mi < 4; ++mi)
        #pragma unroll
        for (int ni = 0; ni < NFR; ++ni)
          acc[mi][ni] = __builtin_amdgcn_mfma_f32_16x16x32_f16(al[mi], bh[ni], acc[mi][ni], 0, 0, 0);
    }
    __builtin_amdgcn_s_setprio(0);

    // stage A(kt+1) into the other buffer; one barrier per K-step
    writeA(buf ^ 1);
    __syncthreads();
  }

  // epilogue: C layout col=lane&15, row=(lane>>4)*4+jj (m89-verified)
  #pragma unroll
  for (int mi = 0; mi < 4; ++mi) {
    #pragma unroll
    for (int jj = 0; jj < 4; ++jj) {
      int lm = wr * 64 + mi * 16 + fq * 4 + jj;
      int gm = m0 + lm;
      if (gm < cnt) {
        int tok = stok[gm];
        float p = sprb[gm];
        float* orow = Out + (size_t)tok * N + n0 + wc * (BN / 2) + fr;
        #pragma unroll
        for (int ni = 0; ni < NFR; ++ni) {
          float v = p * acc[mi][ni][jj];
          if constexpr (ADD) orow[ni * 16] += v; else orow[ni * 16] = v;
        }
      }
    }
  }
}

// fused SwiGLU + down-router: 1 block per token row
__global__ __launch_bounds__(256) void swiglu_router(float* __restrict__ g,
    const float* __restrict__ u, const float* __restrict__ Rd, int* __restrict__ meta)
{
  int t = blockIdx.x, tid = threadIdx.x;
  float part[8];
  #pragma unroll
  for (int e = 0; e < 8; ++e) part[e] = 0.f;
  float* gr = g + (size_t)t * I_DIM;
  const float* ur = u + (size_t)t * I_DIM;
  #pragma unroll
  for (int cc = 0; cc < 4; ++cc) {
    int i = cc * 1024 + tid * 4;
    f32x4 gv = *(const f32x4*)(gr + i);
    f32x4 uv = *(const f32x4*)(ur + i);
    f32x4 iv;
    #pragma unroll
    for (int j = 0; j < 4; ++j) {
      float xx = gv[j];
      iv[j] = (xx / (1.f + expf(-xx))) * uv[j];
    }
    *(f32x4*)(gr + i) = iv;
    #pragma unroll
    for (int e = 0; e < 8; ++e) {
      f32x4 rv = *(const f32x4*)(Rd + (size_t)e * I_DIM + i);
      part[e] += rv[0]*iv[0] + rv[1]*iv[1] + rv[2]*iv[2] + rv[3]*iv[3];
    }
  }
  __shared__ float red[4][8];
  int w = tid >> 6, lane = tid & 63;
  #pragma unroll
  for (int e = 0; e < 8; ++e) {
    float s = wave_sum(part[e]);
    if (lane == 0) red[w][e] = s;
  }
  __syncthreads();
  if (tid == 0) {
    float lg[8];
    #pragma unroll
    for (int e = 0; e < 8; ++e) lg[e] = red[0][e] + red[1][e] + red[2][e] + red[3][e];
    topk_write(meta, 2, t, lg);
  }
}

extern "C" void kernel_launch(void* const* d_in, const int* in_sizes, int n_in,
                              void* d_out, int out_size, void* d_ws, size_t ws_size,
                              hipStream_t stream)
{
  const float* x  = (const float*)d_in[0];
  const float* Rg = (const float*)d_in[1];
  const float* Wg = (const float*)d_in[2];
  const float* Ru = (const float*)d_in[3];
  const float* Wu = (const float*)d_in[4];
  const float* Rd = (const float*)d_in[5];
  const float* Wd = (const float*)d_in[6];
  float* out = (float*)d_out;
  char* ws = (char*)d_ws;

  float* g   = (float*)ws;                              // [T, I] fp32, 67MB
  float* u   = (float*)(ws + (size_t)67108864);         // [T, I] fp32, 67MB
  int*  meta = (int*)(ws + (size_t)134217728);          // ~0.4MB

  hipMemsetAsync(meta, 0, 4096, stream);
  router_gu<<<dim3(T_NUM / 4), 256, 0, stream>>>(x, Rg, Ru, meta);
  scan_tiles<<<dim3(1), 64, 0, stream>>>(meta, 0, 2);
  assign_slots<<<dim3(T_NUM / 256), 256, 0, stream>>>(meta, 0, 2);

  moe_gemm3<3, 0, I_DIM, 128, 32><<<dim3(MAXTILES, 32), 256, 0, stream>>>(x, Wg, g, meta, 0, 0);
  moe_gemm3<3, 1, I_DIM, 128, 32><<<dim3(MAXTILES, 32), 256, 0, stream>>>(x, Wg, g, meta, 0, 1);
  moe_gemm3<3, 0, I_DIM, 128, 32><<<dim3(MAXTILES, 32), 256, 0, stream>>>(x, Wu, u, meta, 1, 0);
  moe_gemm3<3, 1, I_DIM, 128, 32><<<dim3(MAXTILES, 32), 256, 0, stream>>>(x, Wu, u, meta, 1, 1);

  swiglu_router<<<dim3(T_NUM), 256, 0, stream>>>(g, u, Rd, meta);
  scan_tiles<<<dim3(1), 64, 0, stream>>>(meta, 2, 1);
  assign_slots<<<dim3(T_NUM / 256), 256, 0, stream>>>(meta, 2, 1);

  moe_gemm3<1, 0, H_DIM, 64, 128><<<dim3(MAXTILES, 16), 256, 0, stream>>>(g, Wd, out, meta, 2, 0);
  moe_gemm3<1, 1, H_DIM, 64, 128><<<dim3(MAXTILES, 16), 256, 0, stream>>>(g, Wd, out, meta, 2, 1);
}

// Round 4
// 1562.243 us; speedup vs baseline: 1.2081x; 1.2081x over previous
//
#include <hip/hip_runtime.h>
#include <cmath>

typedef float    f32x4 __attribute__((ext_vector_type(4)));
typedef _Float16 f16x8 __attribute__((ext_vector_type(8)));

#define T_NUM 4096
#define H_DIM 1024
#define I_DIM 4096
#define MAXTILES 40

// ---- meta layout (int32 indices into the meta block) ----
#define M_COUNTS   0      // [3][2][8]
#define M_CURSORS  48
#define M_OFFSETS  96
#define M_NTILES   144    // [3][2]
#define M_TILE_E   152    // [6][40]
#define M_TILE_M   392    // [6][40]
#define M_TOPKI    1024   // int  [3][4096][2]
#define M_TOPKP    25600  // f32  [3][4096][2]
#define M_STOK     50176  // int  [3][8192]
#define M_SPRB     74752  // f32  [3][8192]

__device__ __forceinline__ float wave_sum(float v) {
  v += __shfl_xor(v, 32);
  v += __shfl_xor(v, 16);
  v += __shfl_xor(v, 8);
  v += __shfl_xor(v, 4);
  v += __shfl_xor(v, 2);
  v += __shfl_xor(v, 1);
  return v;
}

__device__ __forceinline__ void topk_write(int* meta, int layer, int t, const float* v) {
  int e0 = 0; float v0 = v[0];
  #pragma unroll
  for (int e = 1; e < 8; ++e) { if (v[e] > v0) { v0 = v[e]; e0 = e; } }
  int e1 = 0; float v1 = -3.4e38f;
  #pragma unroll
  for (int e = 0; e < 8; ++e) { if (e != e0 && v[e] > v1) { v1 = v[e]; e1 = e; } }
  float ex = expf(v1 - v0);
  float p0 = 1.f / (1.f + ex);
  float p1 = ex / (1.f + ex);
  meta[M_TOPKI + (layer * T_NUM + t) * 2    ] = e0;
  meta[M_TOPKI + (layer * T_NUM + t) * 2 + 1] = e1;
  ((float*)meta)[M_TOPKP + (layer * T_NUM + t) * 2    ] = p0;
  ((float*)meta)[M_TOPKP + (layer * T_NUM + t) * 2 + 1] = p1;
  atomicAdd(&meta[M_COUNTS + (layer * 2 + 0) * 8 + e0], 1);
  atomicAdd(&meta[M_COUNTS + (layer * 2 + 1) * 8 + e1], 1);
}

__global__ __launch_bounds__(256) void router_gu(const float* __restrict__ x,
    const float* __restrict__ Rg, const float* __restrict__ Ru, int* __restrict__ meta)
{
  int w = threadIdx.x >> 6, lane = threadIdx.x & 63;
  int t = blockIdx.x * 4 + w;
  const float* xr = x + (size_t)t * H_DIM + lane * 4;
  f32x4 xv[4];
  #pragma unroll
  for (int c = 0; c < 4; ++c) xv[c] = *(const f32x4*)(xr + c * 256);
  float lg[8], lu[8];
  #pragma unroll
  for (int e = 0; e < 8; ++e) {
    const float* rg = Rg + (size_t)e * H_DIM + lane * 4;
    const float* ru = Ru + (size_t)e * H_DIM + lane * 4;
    float sg = 0.f, su = 0.f;
    #pragma unroll
    for (int c = 0; c < 4; ++c) {
      f32x4 a = *(const f32x4*)(rg + c * 256);
      f32x4 b = *(const f32x4*)(ru + c * 256);
      sg += a[0]*xv[c][0] + a[1]*xv[c][1] + a[2]*xv[c][2] + a[3]*xv[c][3];
      su += b[0]*xv[c][0] + b[1]*xv[c][1] + b[2]*xv[c][2] + b[3]*xv[c][3];
    }
    lg[e] = wave_sum(sg);
    lu[e] = wave_sum(su);
  }
  if (lane == 0) {
    topk_write(meta, 0, t, lg);
    topk_write(meta, 1, t, lu);
  }
}

__global__ void scan_tiles(int* meta, int l0, int nl) {
  if (threadIdx.x != 0 || blockIdx.x != 0) return;
  for (int l = l0; l < l0 + nl; ++l) {
    int off = 0;
    for (int k = 0; k < 2; ++k) {
      int nt = 0;
      for (int e = 0; e < 8; ++e) {
        int s = (l * 2 + k) * 8 + e;
        meta[M_OFFSETS + s] = off;
        int c = meta[M_COUNTS + s];
        for (int m = 0; m < c; m += 128) {
          meta[M_TILE_E + (l * 2 + k) * MAXTILES + nt] = e;
          meta[M_TILE_M + (l * 2 + k) * MAXTILES + nt] = m;
          ++nt;
        }
        off += c;
      }
      meta[M_NTILES + l * 2 + k] = nt;
    }
  }
}

__global__ __launch_bounds__(256) void assign_slots(int* meta, int l0, int nl) {
  int t = blockIdx.x * blockDim.x + threadIdx.x;
  if (t >= T_NUM) return;
  for (int l = l0; l < l0 + nl; ++l) {
    #pragma unroll
    for (int k = 0; k < 2; ++k) {
      int e  = meta[M_TOPKI + (l * T_NUM + t) * 2 + k];
      float p = ((float*)meta)[M_TOPKP + (l * T_NUM + t) * 2 + k];
      int s = (l * 2 + k) * 8 + e;
      int pos = meta[M_OFFSETS + s] + atomicAdd(&meta[M_CURSORS + s], 1);
      meta[M_STOK + l * 8192 + pos] = t;
      ((float*)meta)[M_SPRB + l * 8192 + pos] = p;
    }
  }
}

// W pre-convert: fp32 [E][N][K] -> tiled f16 hi/lo planes.
// Chunk = (e, nb, kt32) of [fq:4][row:128][8] f16 = 4096 f16 = exactly the
// LDS image global_load_lds produces. (Validated round 2.)
template<int SPLITS>
__global__ __launch_bounds__(256) void convert_w(const float* __restrict__ W,
    _Float16* __restrict__ Whi, _Float16* __restrict__ Wlo, int NB, int KT)
{
  size_t g = (size_t)blockIdx.x * 256 + threadIdx.x;
  int c   = (int)(g >> 9);
  int rem = (int)(g & 511);
  int fq = rem >> 7, r = rem & 127;
  int e  = c / (NB * KT);
  int nb = (c / KT) % NB;
  int kt = c - (c / KT) * KT;
  int K = KT * 32, N = NB * 128;
  const float* src = W + ((size_t)(e * N + nb * 128 + r)) * K + kt * 32 + fq * 8;
  f32x4 v0 = *(const f32x4*)src;
  f32x4 v1 = *(const f32x4*)(src + 4);
  f16x8 h, l;
  #pragma unroll
  for (int q = 0; q < 8; ++q) {
    float v = (q < 4) ? v0[q] : v1[q - 4];
    _Float16 hv = (_Float16)v;
    h[q] = hv;
    l[q] = (_Float16)(v - (float)hv);
  }
  size_t dst = (size_t)c * 4096 + (size_t)rem * 8;
  *(f16x8*)(Whi + dst) = h;
  if constexpr (SPLITS == 3) *(f16x8*)(Wlo + dst) = l;
}

__device__ __forceinline__ void gload16(const _Float16* g, _Float16* l) {
  __builtin_amdgcn_global_load_lds(
      (const __attribute__((address_space(1))) void*)g,
      (__attribute__((address_space(3))) void*)l, 16, 0, 0);
}

// Routed GEMM v4: 128x128 tile, 4 waves (2x2), mfma_f32_16x16x32_f16.
// W: global_load_lds from pre-tiled f16 planes into a 3-buffer LDS ring,
//    staged 2 K-steps ahead. A: gathered fp32 rows -> reg -> hi/lo f16 ->
//    2-buffer LDS, staged 1 step ahead.
// Steady state: ONE compiler vmcnt (at writeA, ~1 iter coverage, transitively
// drains W(j+1)); end-of-iter is lgkmcnt(0) + raw s_barrier. No vmcnt(0).
// KK chunks of 32-k per iter (gate/up: 1, down: 2). SPLITK via blockIdx.z.
template<int SPLITS, int ADD, int N, int NB, int KT, int KK, int KSTR, int SPLITK>
__global__ __launch_bounds__(256) void moe_gemm4(
    const float* __restrict__ Asrc,
    const _Float16* __restrict__ Whi, const _Float16* __restrict__ Wlo,
    float* __restrict__ Out, float* __restrict__ Scr,
    const int* __restrict__ meta, int layer, int kk)
{
  int pass = layer * 2 + kk;
  if ((int)blockIdx.x >= meta[M_NTILES + pass]) return;
  int e    = meta[M_TILE_E + pass * MAXTILES + blockIdx.x];
  int m0   = meta[M_TILE_M + pass * MAXTILES + blockIdx.x];
  int sidx = pass * 8 + e;
  int cnt  = meta[M_COUNTS + sidx];
  int seg  = meta[M_OFFSETS + sidx];
  int n0   = blockIdx.y * 128;
  int kc   = (SPLITK == 2) ? (int)blockIdx.z : 0;

  __shared__ __align__(16) _Float16 sA[2 * 8192];
  __shared__ __align__(16) _Float16 sW[3 * 8192];

  int tid = threadIdx.x, lane = tid & 63, w = tid >> 6;
  int wr = w >> 1, wc = w & 1, fr = lane & 15, fq = lane >> 4;
  int r2 = tid >> 1, half = tid & 1;

  const int*   stok = meta + M_STOK + layer * 8192 + seg;
  const float* sprb = (const float*)meta + M_SPRB + layer * 8192 + seg;

  int ma = m0 + r2; if (ma >= cnt) ma = cnt - 1;
  // A: thread covers row r2, k-chunk half (16 floats for KK=1, 32 for KK=2)
  const float* Abase = Asrc + (size_t)stok[ma] * KSTR + (size_t)kc * KT * KK * 32
                     + half * (KK == 1 ? 16 : 32);

  // W tiled source: panel (e, nb) has KSTR/32 chunks of 4096 f16
  size_t wpanel = (size_t)(e * NB + (int)blockIdx.y) * (KSTR / 32) * 4096
                + (size_t)kc * KT * KK * 4096;
  const _Float16* gWsrc;
  int wdst;
  if constexpr (SPLITS == 3) {
    gWsrc = ((w >> 1) ? Wlo : Whi) + wpanel + (w & 1) * 2048 + lane * 8;
    wdst  = (w >> 1) * 4096 + (w & 1) * 2048;
  } else {
    gWsrc = Whi + wpanel + w * 2048 + lane * 8;
    wdst  = w * 2048;
  }

  auto stageW = [&](int it, int b3) {
    const _Float16* src = gWsrc + (size_t)it * (KK * 4096);
    _Float16* dst = sW + b3 * 8192 + wdst;
    #pragma unroll
    for (int sub = 0; sub < 4; ++sub) gload16(src + sub * 512, dst + sub * 512);
  };

  f32x4 va[KK * 4];
  auto loadA = [&](int it) {
    const float* p = Abase + (size_t)it * (KK * 32);
    #pragma unroll
    for (int q = 0; q < KK * 4; ++q) va[q] = *(const f32x4*)(p + q * 4);
  };
  auto writeA = [&](int ab) {
    if constexpr (SPLITS == 3) {
      #pragma unroll
      for (int j = 0; j < 2; ++j) {
        f16x8 h, l;
        #pragma unroll
        for (int q = 0; q < 8; ++q) {
          float v = va[j * 2 + (q >> 2)][q & 3];
          _Float16 hv = (_Float16)v;
          h[q] = hv;
          l[q] = (_Float16)(v - (float)hv);
        }
        int off = ab * 8192 + ((half * 2 + j) * 128 + r2) * 8;
        *(f16x8*)&sA[off] = h;
        *(f16x8*)&sA[off + 4096] = l;
      }
    } else {
      // KK==2: thread's 32 floats = full chunk `half`
      #pragma unroll
      for (int j = 0; j < 4; ++j) {
        f16x8 h;
        #pragma unroll
        for (int q = 0; q < 8; ++q) h[q] = (_Float16)va[j * 2 + (q >> 2)][q & 3];
        int off = ab * 8192 + half * 4096 + (j * 128 + r2) * 8;
        *(f16x8*)&sA[off] = h;
      }
    }
  };

  int arow = (wr * 64 + fr) * 8;
  int brow = (wc * 64 + fr) * 8;

  f32x4 acc[4][4];
  #pragma unroll
  for (int i = 0; i < 4; ++i)
    #pragma unroll
    for (int j = 0; j < 4; ++j) acc[i][j] = f32x4{0.f, 0.f, 0.f, 0.f};

  // ---- prologue ----
  loadA(0);
  stageW(0, 0);
  stageW(1 < KT ? 1 : 0, 1);
  writeA(0);                       // compiler vmcnt: A(0) done (8 W gloads newer)
  loadA(1 < KT ? 1 : 0);
  __builtin_amdgcn_sched_barrier(0);
  if constexpr (KK == 1) asm volatile("s_waitcnt vmcnt(8)" ::: "memory");
  else                   asm volatile("s_waitcnt vmcnt(12)" ::: "memory");
  asm volatile("s_waitcnt lgkmcnt(0)" ::: "memory");
  __builtin_amdgcn_s_barrier();
  __builtin_amdgcn_sched_barrier(0);

  int b3 = 0;  // W ring index of current iter
  for (int it = 0; it < KT; ++it) {
    int itp2 = it + 2; if (itp2 >= KT) itp2 -= KT;      // wrap: harmless re-stage
    int itp1 = it + 1; if (itp1 >= KT) itp1 -= KT;
    int b3n = b3 + 2; if (b3n >= 3) b3n -= 3;           // (it+2)%3

    stageW(itp2, b3n);                                   // W 2 ahead (4 gloads)
    __builtin_amdgcn_sched_barrier(0);
    writeA((it + 1) & 1);        // compiler waits A(it+1); transitively W(it+1)
    loadA(itp2);                 // next A into flight
    __builtin_amdgcn_sched_barrier(0);

    const _Float16* A0 = sA + (it & 1) * 8192;
    const _Float16* W0 = sW + b3 * 8192;
    __builtin_amdgcn_s_setprio(1);
    if constexpr (SPLITS == 3) {
      f16x8 ah[4], bh[4], t[4];
      #pragma unroll
      for (int mi = 0; mi < 4; ++mi) ah[mi] = *(const f16x8*)(A0 + (fq * 128 + mi * 16) * 8 + arow);
      #pragma unroll
      for (int ni = 0; ni < 4; ++ni) bh[ni] = *(const f16x8*)(W0 + (fq * 128 + ni * 16) * 8 + brow);
      #pragma unroll
      for (int mi = 0; mi < 4; ++mi)
        #pragma unroll
        for (int ni = 0; ni < 4; ++ni)
          acc[mi][ni] = __builtin_amdgcn_mfma_f32_16x16x32_f16(ah[mi], bh[ni], acc[mi][ni], 0, 0, 0);
      #pragma unroll
      for (int ni = 0; ni < 4; ++ni) t[ni] = *(const f16x8*)(W0 + 4096 + (fq * 128 + ni * 16) * 8 + brow);
      #pragma unroll
      for (int mi = 0; mi < 4; ++mi)
        #pragma unroll
        for (int ni = 0; ni < 4; ++ni)
          acc[mi][ni] = __builtin_amdgcn_mfma_f32_16x16x32_f16(ah[mi], t[ni], acc[mi][ni], 0, 0, 0);
      #pragma unroll
      for (int mi = 0; mi < 4; ++mi) t[mi] = *(const f16x8*)(A0 + 4096 + (fq * 128 + mi * 16) * 8 + arow);
      #pragma unroll
      for (int mi = 0; mi < 4; ++mi)
        #pragma unroll
        for (int ni = 0; ni < 4; ++ni)
          acc[mi][ni] = __builtin_amdgcn_mfma_f32_16x16x32_f16(t[mi], bh[ni], acc[mi][ni], 0, 0, 0);
    } else {
      #pragma unroll
      for (int c = 0; c < KK; ++c) {
        f16x8 ah[4], bh[4];
        #pragma unroll
        for (int mi = 0; mi < 4; ++mi) ah[mi] = *(const f16x8*)(A0 + c * 4096 + (fq * 128 + mi * 16) * 8 + arow);
        #pragma unroll
        for (int ni = 0; ni < 4; ++ni) bh[ni] = *(const f16x8*)(W0 + c * 4096 + (fq * 128 + ni * 16) * 8 + brow);
        #pragma unroll
        for (int mi = 0; mi < 4; ++mi)
          #pragma unroll
          for (int ni = 0; ni < 4; ++ni)
            acc[mi][ni] = __builtin_amdgcn_mfma_f32_16x16x32_f16(ah[mi], bh[ni], acc[mi][ni], 0, 0, 0);
      }
    }
    __builtin_amdgcn_s_setprio(0);

    __builtin_amdgcn_sched_barrier(0);
    asm volatile("s_waitcnt lgkmcnt(0)" ::: "memory");   // A ds_writes visible
    __builtin_amdgcn_s_barrier();                        // NO vmcnt drain
    __builtin_amdgcn_sched_barrier(0);
    b3 = b3 + 1; if (b3 == 3) b3 = 0;
  }

  float* dst = (SPLITK == 2 && kc == 1) ? Scr : Out;
  #pragma unroll
  for (int mi = 0; mi < 4; ++mi) {
    #pragma unroll
    for (int jj = 0; jj < 4; ++jj) {
      int lm = wr * 64 + mi * 16 + fq * 4 + jj;
      int gm = m0 + lm;
      if (gm < cnt) {
        int tok = stok[gm];
        float p = sprb[gm];
        float* orow = dst + (size_t)tok * N + n0 + wc * 64 + fr;
        #pragma unroll
        for (int ni = 0; ni < 4; ++ni) {
          float v = p * acc[mi][ni][jj];
          if constexpr (ADD) orow[ni * 16] += v; else orow[ni * 16] = v;
        }
      }
    }
  }
}

// fused SwiGLU + down-router
__global__ __launch_bounds__(256) void swiglu_router(float* __restrict__ g,
    const float* __restrict__ u, const float* __restrict__ Rd, int* __restrict__ meta)
{
  int t = blockIdx.x, tid = threadIdx.x;
  float part[8];
  #pragma unroll
  for (int e = 0; e < 8; ++e) part[e] = 0.f;
  float* gr = g + (size_t)t * I_DIM;
  const float* ur = u + (size_t)t * I_DIM;
  #pragma unroll
  for (int cc = 0; cc < 4; ++cc) {
    int i = cc * 1024 + tid * 4;
    f32x4 gv = *(const f32x4*)(gr + i);
    f32x4 uv = *(const f32x4*)(ur + i);
    f32x4 iv;
    #pragma unroll
    for (int j = 0; j < 4; ++j) {
      float xx = gv[j];
      iv[j] = (xx / (1.f + expf(-xx))) * uv[j];
    }
    *(f32x4*)(gr + i) = iv;
    #pragma unroll
    for (int e = 0; e < 8; ++e) {
      f32x4 rv = *(const f32x4*)(Rd + (size_t)e * I_DIM + i);
      part[e] += rv[0]*iv[0] + rv[1]*iv[1] + rv[2]*iv[2] + rv[3]*iv[3];
    }
  }
  __shared__ float red[4][8];
  int w = tid >> 6, lane = tid & 63;
  #pragma unroll
  for (int e = 0; e < 8; ++e) {
    float s = wave_sum(part[e]);
    if (lane == 0) red[w][e] = s;
  }
  __syncthreads();
  if (tid == 0) {
    float lg[8];
    #pragma unroll
    for (int e = 0; e < 8; ++e) lg[e] = red[0][e] + red[1][e] + red[2][e] + red[3][e];
    topk_write(meta, 2, t, lg);
  }
}

__global__ __launch_bounds__(256) void combine_kernel(float* __restrict__ out,
                                                      const float* __restrict__ scr)
{
  int i = blockIdx.x * 1024 + threadIdx.x * 4;
  f32x4 a = *(const f32x4*)(out + i);
  f32x4 b = *(const f32x4*)(scr + i);
  #pragma unroll
  for (int j = 0; j < 4; ++j) a[j] += b[j];
  *(f32x4*)(out + i) = a;
}

extern "C" void kernel_launch(void* const* d_in, const int* in_sizes, int n_in,
                              void* d_out, int out_size, void* d_ws, size_t ws_size,
                              hipStream_t stream)
{
  const float* x  = (const float*)d_in[0];
  const float* Rg = (const float*)d_in[1];
  const float* Wg = (const float*)d_in[2];
  const float* Ru = (const float*)d_in[3];
  const float* Wu = (const float*)d_in[4];
  const float* Rd = (const float*)d_in[5];
  const float* Wd = (const float*)d_in[6];
  float* out = (float*)d_out;
  char* ws = (char*)d_ws;

  _Float16* Wth = (_Float16*)ws;                          // 67MB tiled hi plane
  _Float16* Wtl = (_Float16*)(ws + (size_t)67108864);     // 67MB tiled lo plane
  float* g   = (float*)(ws + (size_t)134217728);          // [T, I] fp32
  float* u   = (float*)(ws + (size_t)201326592);          // [T, I] fp32 (reused as down scratch)
  int*  meta = (int*)(ws + (size_t)268435456);            // ~0.4MB

  hipMemsetAsync(meta, 0, 4096, stream);
  router_gu<<<dim3(T_NUM / 4), 256, 0, stream>>>(x, Rg, Ru, meta);
  scan_tiles<<<dim3(1), 64, 0, stream>>>(meta, 0, 2);
  assign_slots<<<dim3(T_NUM / 256), 256, 0, stream>>>(meta, 0, 2);

  convert_w<3><<<dim3(16384), 256, 0, stream>>>(Wg, Wth, Wtl, 32, 32);
  moe_gemm4<3, 0, I_DIM, 32, 32, 1, 1024, 1><<<dim3(MAXTILES, 32, 1), 256, 0, stream>>>(
      x, Wth, Wtl, g, g, meta, 0, 0);
  moe_gemm4<3, 1, I_DIM, 32, 32, 1, 1024, 1><<<dim3(MAXTILES, 32, 1), 256, 0, stream>>>(
      x, Wth, Wtl, g, g, meta, 0, 1);

  convert_w<3><<<dim3(16384), 256, 0, stream>>>(Wu, Wth, Wtl, 32, 32);
  moe_gemm4<3, 0, I_DIM, 32, 32, 1, 1024, 1><<<dim3(MAXTILES, 32, 1), 256, 0, stream>>>(
      x, Wth, Wtl, u, u, meta, 1, 0);
  moe_gemm4<3, 1, I_DIM, 32, 32, 1, 1024, 1><<<dim3(MAXTILES, 32, 1), 256, 0, stream>>>(
      x, Wth, Wtl, u, u, meta, 1, 1);

  swiglu_router<<<dim3(T_NUM), 256, 0, stream>>>(g, u, Rd, meta);
  scan_tiles<<<dim3(1), 64, 0, stream>>>(meta, 2, 1);
  assign_slots<<<dim3(T_NUM / 256), 256, 0, stream>>>(meta, 2, 1);

  convert_w<1><<<dim3(16384), 256, 0, stream>>>(Wd, Wth, Wth, 8, 128);
  float* dscr = u;  // [T,1024] scratch in dead u buffer
  moe_gemm4<1, 0, H_DIM, 8, 32, 2, 4096, 2><<<dim3(MAXTILES, 8, 2), 256, 0, stream>>>(
      g, Wth, Wth, out, dscr, meta, 2, 0);
  moe_gemm4<1, 1, H_DIM, 8, 32, 2, 4096, 2><<<dim3(MAXTILES, 8, 2), 256, 0, stream>>>(
      g, Wth, Wth, out, dscr, meta, 2, 1);
  combine_kernel<<<dim3(T_NUM), 256, 0, stream>>>(out, dscr);
}

// Round 5
// 1472.874 us; speedup vs baseline: 1.2814x; 1.0607x over previous
//
#include <hip/hip_runtime.h>
#include <cmath>

typedef float    f32x4 __attribute__((ext_vector_type(4)));
typedef _Float16 f16x8 __attribute__((ext_vector_type(8)));

#define T_NUM 4096
#define H_DIM 1024
#define I_DIM 4096
#define MAXTILES 40

// ---- meta layout (int32 indices into the meta block) ----
#define M_COUNTS   0      // [3][2][8]
#define M_CURSORS  48
#define M_OFFSETS  96
#define M_NTILES   144    // [3][2]
#define M_TILE_E   152    // [6][40]
#define M_TILE_M   392    // [6][40]
#define M_TOPKI    1024   // int  [3][4096][2]
#define M_TOPKP    25600  // f32  [3][4096][2]
#define M_STOK     50176  // int  [3][8192]
#define M_SPRB     74752  // f32  [3][8192]

__device__ __forceinline__ float wave_sum(float v) {
  v += __shfl_xor(v, 32);
  v += __shfl_xor(v, 16);
  v += __shfl_xor(v, 8);
  v += __shfl_xor(v, 4);
  v += __shfl_xor(v, 2);
  v += __shfl_xor(v, 1);
  return v;
}

__device__ __forceinline__ void topk_write(int* meta, int layer, int t, const float* v) {
  int e0 = 0; float v0 = v[0];
  #pragma unroll
  for (int e = 1; e < 8; ++e) { if (v[e] > v0) { v0 = v[e]; e0 = e; } }
  int e1 = 0; float v1 = -3.4e38f;
  #pragma unroll
  for (int e = 0; e < 8; ++e) { if (e != e0 && v[e] > v1) { v1 = v[e]; e1 = e; } }
  float ex = expf(v1 - v0);
  float p0 = 1.f / (1.f + ex);
  float p1 = ex / (1.f + ex);
  meta[M_TOPKI + (layer * T_NUM + t) * 2    ] = e0;
  meta[M_TOPKI + (layer * T_NUM + t) * 2 + 1] = e1;
  ((float*)meta)[M_TOPKP + (layer * T_NUM + t) * 2    ] = p0;
  ((float*)meta)[M_TOPKP + (layer * T_NUM + t) * 2 + 1] = p1;
  atomicAdd(&meta[M_COUNTS + (layer * 2 + 0) * 8 + e0], 1);
  atomicAdd(&meta[M_COUNTS + (layer * 2 + 1) * 8 + e1], 1);
}

__global__ __launch_bounds__(256) void router_gu(const float* __restrict__ x,
    const float* __restrict__ Rg, const float* __restrict__ Ru, int* __restrict__ meta)
{
  int w = threadIdx.x >> 6, lane = threadIdx.x & 63;
  int t = blockIdx.x * 4 + w;
  const float* xr = x + (size_t)t * H_DIM + lane * 4;
  f32x4 xv[4];
  #pragma unroll
  for (int c = 0; c < 4; ++c) xv[c] = *(const f32x4*)(xr + c * 256);
  float lg[8], lu[8];
  #pragma unroll
  for (int e = 0; e < 8; ++e) {
    const float* rg = Rg + (size_t)e * H_DIM + lane * 4;
    const float* ru = Ru + (size_t)e * H_DIM + lane * 4;
    float sg = 0.f, su = 0.f;
    #pragma unroll
    for (int c = 0; c < 4; ++c) {
      f32x4 a = *(const f32x4*)(rg + c * 256);
      f32x4 b = *(const f32x4*)(ru + c * 256);
      sg += a[0]*xv[c][0] + a[1]*xv[c][1] + a[2]*xv[c][2] + a[3]*xv[c][3];
      su += b[0]*xv[c][0] + b[1]*xv[c][1] + b[2]*xv[c][2] + b[3]*xv[c][3];
    }
    lg[e] = wave_sum(sg);
    lu[e] = wave_sum(su);
  }
  if (lane == 0) {
    topk_write(meta, 0, t, lg);
    topk_write(meta, 1, t, lu);
  }
}

__global__ void scan_tiles(int* meta, int l0, int nl) {
  if (threadIdx.x != 0 || blockIdx.x != 0) return;
  for (int l = l0; l < l0 + nl; ++l) {
    int off = 0;
    for (int k = 0; k < 2; ++k) {
      int nt = 0;
      for (int e = 0; e < 8; ++e) {
        int s = (l * 2 + k) * 8 + e;
        meta[M_OFFSETS + s] = off;
        int c = meta[M_COUNTS + s];
        for (int m = 0; m < c; m += 128) {
          meta[M_TILE_E + (l * 2 + k) * MAXTILES + nt] = e;
          meta[M_TILE_M + (l * 2 + k) * MAXTILES + nt] = m;
          ++nt;
        }
        off += c;
      }
      meta[M_NTILES + l * 2 + k] = nt;
    }
  }
}

__global__ __launch_bounds__(256) void assign_slots(int* meta, int l0, int nl) {
  int t = blockIdx.x * blockDim.x + threadIdx.x;
  if (t >= T_NUM) return;
  for (int l = l0; l < l0 + nl; ++l) {
    #pragma unroll
    for (int k = 0; k < 2; ++k) {
      int e  = meta[M_TOPKI + (l * T_NUM + t) * 2 + k];
      float p = ((float*)meta)[M_TOPKP + (l * T_NUM + t) * 2 + k];
      int s = (l * 2 + k) * 8 + e;
      int pos = meta[M_OFFSETS + s] + atomicAdd(&meta[M_CURSORS + s], 1);
      meta[M_STOK + l * 8192 + pos] = t;
      ((float*)meta)[M_SPRB + l * 8192 + pos] = p;
    }
  }
}

// W pre-convert: fp32 [E][N][K] -> tiled f16 hi/lo planes.
// Chunk = (e, nb, kt32) of [fq:4][row:128][8] f16 = 4096 f16. (Validated r2/r4.)
template<int SPLITS>
__global__ __launch_bounds__(256) void convert_w(const float* __restrict__ W,
    _Float16* __restrict__ Whi, _Float16* __restrict__ Wlo, int NB, int KT)
{
  size_t g = (size_t)blockIdx.x * 256 + threadIdx.x;
  int c   = (int)(g >> 9);
  int rem = (int)(g & 511);
  int fq = rem >> 7, r = rem & 127;
  int e  = c / (NB * KT);
  int nb = (c / KT) % NB;
  int kt = c - (c / KT) * KT;
  int K = KT * 32, N = NB * 128;
  const float* src = W + ((size_t)(e * N + nb * 128 + r)) * K + kt * 32 + fq * 8;
  f32x4 v0 = *(const f32x4*)src;
  f32x4 v1 = *(const f32x4*)(src + 4);
  f16x8 h, l;
  #pragma unroll
  for (int q = 0; q < 8; ++q) {
    float v = (q < 4) ? v0[q] : v1[q - 4];
    _Float16 hv = (_Float16)v;
    h[q] = hv;
    l[q] = (_Float16)(v - (float)hv);
  }
  size_t dst = (size_t)c * 4096 + (size_t)rem * 8;
  *(f16x8*)(Whi + dst) = h;
  if constexpr (SPLITS == 3) *(f16x8*)(Wlo + dst) = l;
}

// Routed GEMM v5: 128x128 tile, 4 waves (2x2), mfma_f32_16x16x32_f16.
// W: DIRECT global->register fragment loads from pre-tiled f16 planes
//    (16B/lane coalesced), double-buffered 1 K-step ahead in named register
//    sets (2x-unrolled loop, static indexing). No block-wide wait touches W.
// A: gathered fp32 rows -> reg -> f16 hi/lo -> LDS dbuf (32KB total).
// Per K-step barrier protects ONLY the A LDS buffers (lgkmcnt, no vmcnt).
// 1D grid, bijective XCD chunking (ny-outer) for W-panel L2 residency.
template<int SPLITS, int ADD, int N, int NB, int KT, int KK, int KSTR, int SPLITK>
__global__ __launch_bounds__(256, 2) void moe_gemm5(
    const float* __restrict__ Asrc,
    const _Float16* __restrict__ Whi, const _Float16* __restrict__ Wlo,
    float* __restrict__ Out, float* __restrict__ Scr,
    const int* __restrict__ meta, int layer, int kk)
{
  constexpr int KL = (SPLITS == 3) ? KK : 1;
  constexpr int NWG = MAXTILES * NB * SPLITK;
  constexpr int Q8 = NWG / 8;

  // XCD-chunked bijective decode (m204): XCD i gets logical [i*Q8,(i+1)*Q8)
  int orig = (int)blockIdx.x;
  int logical = (orig & 7) * Q8 + (orig >> 3);
  int kc, l2;
  if constexpr (SPLITK == 2) { kc = logical / (MAXTILES * NB); l2 = logical - kc * (MAXTILES * NB); }
  else                       { kc = 0; l2 = logical; }
  int ny = l2 / MAXTILES;
  int tx = l2 - ny * MAXTILES;

  int pass = layer * 2 + kk;
  if (tx >= meta[M_NTILES + pass]) return;
  int e    = meta[M_TILE_E + pass * MAXTILES + tx];
  int m0   = meta[M_TILE_M + pass * MAXTILES + tx];
  int sidx = pass * 8 + e;
  int cnt  = meta[M_COUNTS + sidx];
  int seg  = meta[M_OFFSETS + sidx];
  int n0   = ny * 128;

  __shared__ __align__(16) _Float16 sA[2 * 8192];

  int tid = threadIdx.x, lane = tid & 63, w = tid >> 6;
  int wr = w >> 1, wc = w & 1, fr = lane & 15, fq = lane >> 4;
  int r2 = tid >> 1, half = tid & 1;

  const int*   stok = meta + M_STOK + layer * 8192 + seg;
  const float* sprb = (const float*)meta + M_SPRB + layer * 8192 + seg;

  int ma = m0 + r2; if (ma >= cnt) ma = cnt - 1;
  const float* Abase = Asrc + (size_t)stok[ma] * KSTR + (size_t)kc * KT * KK * 32
                     + half * (KK == 1 ? 16 : 32);

  // W per-lane fragment base inside tiled panel (e, ny)
  size_t wpanel = (size_t)(e * NB + ny) * (KSTR / 32) * 4096
                + (size_t)kc * KT * KK * 4096;
  const _Float16* WhL = Whi + wpanel + (fq * 128 + wc * 64 + fr) * 8;
  const _Float16* WlL = Wlo + wpanel + (fq * 128 + wc * 64 + fr) * 8;

  f32x4 va[KK * 4];
  auto loadA = [&](int it) {
    const float* p = Abase + (size_t)it * (KK * 32);
    #pragma unroll
    for (int q = 0; q < KK * 4; ++q) va[q] = *(const f32x4*)(p + q * 4);
  };
  auto writeA = [&](int ab) {
    if constexpr (SPLITS == 3) {
      #pragma unroll
      for (int j = 0; j < 2; ++j) {
        f16x8 h, l;
        #pragma unroll
        for (int q = 0; q < 8; ++q) {
          float v = va[j * 2 + (q >> 2)][q & 3];
          _Float16 hv = (_Float16)v;
          h[q] = hv;
          l[q] = (_Float16)(v - (float)hv);
        }
        int off = ab * 8192 + ((half * 2 + j) * 128 + r2) * 8;
        *(f16x8*)&sA[off] = h;
        *(f16x8*)&sA[off + 4096] = l;
      }
    } else {
      #pragma unroll
      for (int j = 0; j < 4; ++j) {
        f16x8 h;
        #pragma unroll
        for (int q = 0; q < 8; ++q) h[q] = (_Float16)va[j * 2 + (q >> 2)][q & 3];
        int off = ab * 8192 + half * 4096 + (j * 128 + r2) * 8;
        *(f16x8*)&sA[off] = h;
      }
    }
  };

  auto loadW = [&](int it, f16x8 (&wh)[KK][4], f16x8 (&wl)[KL][4]) {
    #pragma unroll
    for (int c = 0; c < KK; ++c) {
      size_t cb = (size_t)(it * KK + c) * 4096;
      #pragma unroll
      for (int ni = 0; ni < 4; ++ni)
        wh[c][ni] = *(const f16x8*)(WhL + cb + ni * 128);
      if constexpr (SPLITS == 3) {
        #pragma unroll
        for (int ni = 0; ni < 4; ++ni)
          wl[c][ni] = *(const f16x8*)(WlL + cb + ni * 128);
      }
    }
  };

  int arow = (wr * 64 + fr) * 8;

  f32x4 acc[4][4];
  #pragma unroll
  for (int i = 0; i < 4; ++i)
    #pragma unroll
    for (int j = 0; j < 4; ++j) acc[i][j] = f32x4{0.f, 0.f, 0.f, 0.f};

  f16x8 w0h[KK][4], w0l[KL][4], w1h[KK][4], w1l[KL][4];

  auto step = [&](int it, f16x8 (&cwh)[KK][4], f16x8 (&cwl)[KL][4],
                          f16x8 (&nwh)[KK][4], f16x8 (&nwl)[KL][4]) {
    int itn = (it + 1 < KT) ? it + 1 : KT - 1;
    loadW(itn, nwh, nwl);                       // prefetch next step's W (VMEM)
    int buf = it & 1;
    const _Float16* A0 = sA + buf * 8192;

    __builtin_amdgcn_s_setprio(1);
    if constexpr (SPLITS == 3) {
      f16x8 ah[4], al[4];
      #pragma unroll
      for (int mi = 0; mi < 4; ++mi) ah[mi] = *(const f16x8*)(A0 + (fq * 128 + mi * 16) * 8 + arow);
      #pragma unroll
      for (int mi = 0; mi < 4; ++mi) al[mi] = *(const f16x8*)(A0 + 4096 + (fq * 128 + mi * 16) * 8 + arow);
      #pragma unroll
      for (int mi = 0; mi < 4; ++mi)
        #pragma unroll
        for (int ni = 0; ni < 4; ++ni)
          acc[mi][ni] = __builtin_amdgcn_mfma_f32_16x16x32_f16(ah[mi], cwh[0][ni], acc[mi][ni], 0, 0, 0);
      #pragma unroll
      for (int mi = 0; mi < 4; ++mi)
        #pragma unroll
        for (int ni = 0; ni < 4; ++ni)
          acc[mi][ni] = __builtin_amdgcn_mfma_f32_16x16x32_f16(ah[mi], cwl[0][ni], acc[mi][ni], 0, 0, 0);
      #pragma unroll
      for (int mi = 0; mi < 4; ++mi)
        #pragma unroll
        for (int ni = 0; ni < 4; ++ni)
          acc[mi][ni] = __builtin_amdgcn_mfma_f32_16x16x32_f16(al[mi], cwh[0][ni], acc[mi][ni], 0, 0, 0);
    } else {
      #pragma unroll
      for (int c = 0; c < KK; ++c) {
        f16x8 ah[4];
        #pragma unroll
        for (int mi = 0; mi < 4; ++mi) ah[mi] = *(const f16x8*)(A0 + c * 4096 + (fq * 128 + mi * 16) * 8 + arow);
        #pragma unroll
        for (int mi = 0; mi < 4; ++mi)
          #pragma unroll
          for (int ni = 0; ni < 4; ++ni)
            acc[mi][ni] = __builtin_amdgcn_mfma_f32_16x16x32_f16(ah[mi], cwh[c][ni], acc[mi][ni], 0, 0, 0);
      }
    }
    __builtin_amdgcn_s_setprio(0);

    writeA((it + 1) & 1);                        // waits va (A it+1) precisely
    int itA = (it + 2 < KT) ? it + 2 : KT - 1;
    loadA(itA);                                  // next A into flight
    __builtin_amdgcn_sched_barrier(0);
    asm volatile("s_waitcnt lgkmcnt(0)" ::: "memory");
    __builtin_amdgcn_s_barrier();                // protects sA only; W uncoupled
    __builtin_amdgcn_sched_barrier(0);
  };

  // ---- prologue ----
  loadW(0, w0h, w0l);
  loadA(0);
  writeA(0);
  loadA(1 < KT ? 1 : 0);
  __builtin_amdgcn_sched_barrier(0);
  asm volatile("s_waitcnt lgkmcnt(0)" ::: "memory");
  __builtin_amdgcn_s_barrier();
  __builtin_amdgcn_sched_barrier(0);

  for (int it = 0; it < KT; it += 2) {
    step(it,     w0h, w0l, w1h, w1l);
    step(it + 1, w1h, w1l, w0h, w0l);
  }

  float* dst = (SPLITK == 2 && kc == 1) ? Scr : Out;
  #pragma unroll
  for (int mi = 0; mi < 4; ++mi) {
    #pragma unroll
    for (int jj = 0; jj < 4; ++jj) {
      int lm = wr * 64 + mi * 16 + fq * 4 + jj;
      int gm = m0 + lm;
      if (gm < cnt) {
        int tok = stok[gm];
        float p = sprb[gm];
        float* orow = dst + (size_t)tok * N + n0 + wc * 64 + fr;
        #pragma unroll
        for (int ni = 0; ni < 4; ++ni) {
          float v = p * acc[mi][ni][jj];
          if constexpr (ADD) orow[ni * 16] += v; else orow[ni * 16] = v;
        }
      }
    }
  }
}

// fused SwiGLU + down-router
__global__ __launch_bounds__(256) void swiglu_router(float* __restrict__ g,
    const float* __restrict__ u, const float* __restrict__ Rd, int* __restrict__ meta)
{
  int t = blockIdx.x, tid = threadIdx.x;
  float part[8];
  #pragma unroll
  for (int e = 0; e < 8; ++e) part[e] = 0.f;
  float* gr = g + (size_t)t * I_DIM;
  const float* ur = u + (size_t)t * I_DIM;
  #pragma unroll
  for (int cc = 0; cc < 4; ++cc) {
    int i = cc * 1024 + tid * 4;
    f32x4 gv = *(const f32x4*)(gr + i);
    f32x4 uv = *(const f32x4*)(ur + i);
    f32x4 iv;
    #pragma unroll
    for (int j = 0; j < 4; ++j) {
      float xx = gv[j];
      iv[j] = (xx / (1.f + expf(-xx))) * uv[j];
    }
    *(f32x4*)(gr + i) = iv;
    #pragma unroll
    for (int e = 0; e < 8; ++e) {
      f32x4 rv = *(const f32x4*)(Rd + (size_t)e * I_DIM + i);
      part[e] += rv[0]*iv[0] + rv[1]*iv[1] + rv[2]*iv[2] + rv[3]*iv[3];
    }
  }
  __shared__ float red[4][8];
  int w = tid >> 6, lane = tid & 63;
  #pragma unroll
  for (int e = 0; e < 8; ++e) {
    float s = wave_sum(part[e]);
    if (lane == 0) red[w][e] = s;
  }
  __syncthreads();
  if (tid == 0) {
    float lg[8];
    #pragma unroll
    for (int e = 0; e < 8; ++e) lg[e] = red[0][e] + red[1][e] + red[2][e] + red[3][e];
    topk_write(meta, 2, t, lg);
  }
}

__global__ __launch_bounds__(256) void combine_kernel(float* __restrict__ out,
                                                      const float* __restrict__ scr)
{
  int i = blockIdx.x * 1024 + threadIdx.x * 4;
  f32x4 a = *(const f32x4*)(out + i);
  f32x4 b = *(const f32x4*)(scr + i);
  #pragma unroll
  for (int j = 0; j < 4; ++j) a[j] += b[j];
  *(f32x4*)(out + i) = a;
}

extern "C" void kernel_launch(void* const* d_in, const int* in_sizes, int n_in,
                              void* d_out, int out_size, void* d_ws, size_t ws_size,
                              hipStream_t stream)
{
  const float* x  = (const float*)d_in[0];
  const float* Rg = (const float*)d_in[1];
  const float* Wg = (const float*)d_in[2];
  const float* Ru = (const float*)d_in[3];
  const float* Wu = (const float*)d_in[4];
  const float* Rd = (const float*)d_in[5];
  const float* Wd = (const float*)d_in[6];
  float* out = (float*)d_out;
  char* ws = (char*)d_ws;

  _Float16* Wth = (_Float16*)ws;                          // 67MB tiled hi plane
  _Float16* Wtl = (_Float16*)(ws + (size_t)67108864);     // 67MB tiled lo plane
  float* g   = (float*)(ws + (size_t)134217728);          // [T, I] fp32
  float* u   = (float*)(ws + (size_t)201326592);          // [T, I] fp32 (reused as down scratch)
  int*  meta = (int*)(ws + (size_t)268435456);            // ~0.4MB

  hipMemsetAsync(meta, 0, 4096, stream);
  router_gu<<<dim3(T_NUM / 4), 256, 0, stream>>>(x, Rg, Ru, meta);
  scan_tiles<<<dim3(1), 64, 0, stream>>>(meta, 0, 2);
  assign_slots<<<dim3(T_NUM / 256), 256, 0, stream>>>(meta, 0, 2);

  convert_w<3><<<dim3(16384), 256, 0, stream>>>(Wg, Wth, Wtl, 32, 32);
  moe_gemm5<3, 0, I_DIM, 32, 32, 1, 1024, 1><<<dim3(MAXTILES * 32), 256, 0, stream>>>(
      x, Wth, Wtl, g, g, meta, 0, 0);
  moe_gemm5<3, 1, I_DIM, 32, 32, 1, 1024, 1><<<dim3(MAXTILES * 32), 256, 0, stream>>>(
      x, Wth, Wtl, g, g, meta, 0, 1);

  convert_w<3><<<dim3(16384), 256, 0, stream>>>(Wu, Wth, Wtl, 32, 32);
  moe_gemm5<3, 0, I_DIM, 32, 32, 1, 1024, 1><<<dim3(MAXTILES * 32), 256, 0, stream>>>(
      x, Wth, Wtl, u, u, meta, 1, 0);
  moe_gemm5<3, 1, I_DIM, 32, 32, 1, 1024, 1><<<dim3(MAXTILES * 32), 256, 0, stream>>>(
      x, Wth, Wtl, u, u, meta, 1, 1);

  swiglu_router<<<dim3(T_NUM), 256, 0, stream>>>(g, u, Rd, meta);
  scan_tiles<<<dim3(1), 64, 0, stream>>>(meta, 2, 1);
  assign_slots<<<dim3(T_NUM / 256), 256, 0, stream>>>(meta, 2, 1);

  convert_w<1><<<dim3(16384), 256, 0, stream>>>(Wd, Wth, Wth, 8, 128);
  float* dscr = u;  // [T,1024] scratch in dead u buffer
  moe_gemm5<1, 0, H_DIM, 8, 32, 2, 4096, 2><<<dim3(MAXTILES * 8 * 2), 256, 0, stream>>>(
      g, Wth, Wth, out, dscr, meta, 2, 0);
  moe_gemm5<1, 1, H_DIM, 8, 32, 2, 4096, 2><<<dim3(MAXTILES * 8 * 2), 256, 0, stream>>>(
      g, Wth, Wth, out, dscr, meta, 2, 1);
  combine_kernel<<<dim3(T_NUM), 256, 0, stream>>>(out, dscr);
}